// Round 10
// baseline (183.814 us; speedup 1.0000x reference)
//
#include <hip/hip_runtime.h>
#include <stdint.h>
#include <stddef.h>

#define NB 2
#define NN 8000
#define NC 64
#define NKT 500          // N/16 key tiles
#define STAGE_KT 5       // key tiles per LDS stage buffer (12.8 KB)
#define LOG2E 1.44269504f
#define NQB 32           // ceil(500 qtiles / 16 per block)

// ---- workspace layout (bytes) ----
// kv per tile (2560 B): f frag (512 B) + h01 interleaved (1024 B) + h23 (1024 B)
#define KV_BYTES  ((size_t)NB * NKT * 2560)         // 2,560,000
#define GB_OFF    KV_BYTES                          // g frags
#define GB_BYTES  ((size_t)NB * NKT * 64 * 8)       // 512,000
#define PML_OFF   (GB_OFF + GB_BYTES)               // l[16] per (b,qt,split)

__host__ __device__ constexpr size_t pml_bytes(int s) { return (size_t)NB * NKT * s * 16 * 4; }
__host__ __device__ constexpr size_t po_off(int s)    { return PML_OFF + pml_bytes(s); }
// partial O: per (b,qt,split) 16 rows x 16 j x uint2 (4 bf16) = 2048 B
__host__ __device__ constexpr size_t po_bytes(int s)  { return (size_t)NB * NKT * s * 2048; }

typedef float f32x4 __attribute__((ext_vector_type(4)));
typedef short s16x4 __attribute__((ext_vector_type(4)));

__device__ inline short f2bf(float f) {                // RNE to bf16 (bitwise, proven)
    union { float f; uint32_t u; } v; v.f = f;
    uint32_t u = v.u + 0x7FFFu + ((v.u >> 16) & 1u);
    return (short)(u >> 16);
}
// raw v_exp_f32: 2^x in ONE instruction (libm wrapper is ~10 VALU ops).
__device__ inline float fexp2(float x) { return __builtin_amdgcn_exp2f(x); }
// pack {hi16(a), hi16(b)} -> one word in ONE v_perm_b32 (truncation to bf16)
__device__ inline uint32_t pack_trunc(uint32_t a_lo, uint32_t b_hi) {
    return __builtin_amdgcn_perm(b_hi, a_lo, 0x07060302u);
}

// ---------------------------------------------------------------------------
// Kernel 1: projections (R8-exact). Grid 250 x 256; per block 4 key tiles,
// one wave each: f = x(Wf*log2e), g = xWg, h = xWh, stored in MFMA fragment
// order (bf16). kv per tile: f A-frag (64 uint2) | h01 (64 uint4) | h23;
// gB[b][qt][lane] = g B-frag. mfma_f32_16x16x16_bf16 maps: A row=lane&15,
// k=(lane>>4)*4+e ; B col=lane&15,k=(lane>>4)*4+e ; C/D col=lane&15,
// row=(lane>>4)*4+reg.
// ---------------------------------------------------------------------------
__global__ __launch_bounds__(256) void proj_kernel(
    const float* __restrict__ x,
    const float* __restrict__ Wf,
    const float* __restrict__ Wg,
    const float* __restrict__ Wh,
    uint8_t* __restrict__ ws)
{
    __shared__ float Wh_s[64][68];
    __shared__ float Wf_s[64][8];
    __shared__ float Wg_s[64][8];
    __shared__ float x_s[4][16][68];
    __shared__ float h_s[4][16][68];

    const int tid = threadIdx.x;
    const int L = tid & 63, w = tid >> 6;
    const int lane16 = L & 15, g4 = L >> 4;

    for (int i = tid; i < 64 * 64; i += 256) Wh_s[i >> 6][i & 63] = Wh[i];
    for (int i = tid; i < 64 * 8; i += 256) {
        Wf_s[i >> 3][i & 7] = Wf[i] * LOG2E;   // scores in log2 domain
        Wg_s[i >> 3][i & 7] = Wg[i];
    }

    const int ktg = blockIdx.x * 4 + w;      // 0..999
    const int b = ktg / NKT, ktb = ktg % NKT;
    const float* xsrc = x + ((size_t)b * NN + (size_t)ktb * 16) * NC;

    #pragma unroll
    for (int i = 0; i < 4; i++) {
        int F = i * 256 + L * 4;
        f32x4 v = *(const f32x4*)(xsrc + F);
        *(f32x4*)&x_s[w][F >> 6][F & 63] = v;
    }
    __syncthreads();

    uint2* kv2 = (uint2*)ws;
    uint4* kv4 = (uint4*)ws;
    uint2* gB  = (uint2*)(ws + GB_OFF);
    const size_t kt = (size_t)(b * NKT + ktb);

    {
        float fa0 = 0, fa1 = 0, fa2 = 0, fa3 = 0;
        float ga0 = 0, ga1 = 0, ga2 = 0, ga3 = 0;
        const int d0 = (g4 & 1) * 4;
        #pragma unroll 4
        for (int k = 0; k < 64; k++) {
            float xv = x_s[w][lane16][k];
            fa0 += xv * Wf_s[k][d0 + 0]; fa1 += xv * Wf_s[k][d0 + 1];
            fa2 += xv * Wf_s[k][d0 + 2]; fa3 += xv * Wf_s[k][d0 + 3];
            ga0 += xv * Wg_s[k][d0 + 0]; ga1 += xv * Wg_s[k][d0 + 1];
            ga2 += xv * Wg_s[k][d0 + 2]; ga3 += xv * Wg_s[k][d0 + 3];
        }
        const bool valid = (g4 < 2);
        union { s16x4 v; uint2 u; } fp, gp;
        fp.v[0] = valid ? f2bf(fa0) : (short)0;
        fp.v[1] = valid ? f2bf(fa1) : (short)0;
        fp.v[2] = valid ? f2bf(fa2) : (short)0;
        fp.v[3] = valid ? f2bf(fa3) : (short)0;
        gp.v[0] = valid ? f2bf(ga0) : (short)0;
        gp.v[1] = valid ? f2bf(ga1) : (short)0;
        gp.v[2] = valid ? f2bf(ga2) : (short)0;
        gp.v[3] = valid ? f2bf(ga3) : (short)0;
        kv2[kt * 320 + L] = fp.u;              // f: first 64 uint2 of the tile
        gB[kt * 64 + L] = gp.u;
    }

    {
        float ha[16];
        #pragma unroll
        for (int i = 0; i < 16; i++) ha[i] = 0.f;
        const int c0 = g4 * 16;
        for (int k = 0; k < 64; k++) {
            float xv = x_s[w][lane16][k];
            const f32x4 w0 = *(const f32x4*)&Wh_s[k][c0 + 0];
            const f32x4 w1 = *(const f32x4*)&Wh_s[k][c0 + 4];
            const f32x4 w2 = *(const f32x4*)&Wh_s[k][c0 + 8];
            const f32x4 w3 = *(const f32x4*)&Wh_s[k][c0 + 12];
            #pragma unroll
            for (int e = 0; e < 4; e++) {
                ha[e]      += xv * w0[e];
                ha[4 + e]  += xv * w1[e];
                ha[8 + e]  += xv * w2[e];
                ha[12 + e] += xv * w3[e];
            }
        }
        #pragma unroll
        for (int i = 0; i < 4; i++) {
            f32x4 t; t[0] = ha[4*i]; t[1] = ha[4*i+1]; t[2] = ha[4*i+2]; t[3] = ha[4*i+3];
            *(f32x4*)&h_s[w][lane16][c0 + 4 * i] = t;
        }
    }
    __syncthreads();

    {
        union { s16x4 v; uint2 u; } hp[4];
        #pragma unroll
        for (int cb = 0; cb < 4; cb++)
            #pragma unroll
            for (int e = 0; e < 4; e++)
                hp[cb].v[e] = f2bf(h_s[w][g4 * 4 + e][cb * 16 + lane16]);
        uint4 h01, h23;
        h01.x = hp[0].u.x; h01.y = hp[0].u.y; h01.z = hp[1].u.x; h01.w = hp[1].u.y;
        h23.x = hp[2].u.x; h23.y = hp[2].u.y; h23.z = hp[3].u.x; h23.w = hp[3].u.y;
        kv4[kt * 160 + 32 + L] = h01;
        kv4[kt * 160 + 96 + L] = h23;
    }
}

// softmax + pack for one q-tile's 4 scores
#define SM_PACK(sv, l, pp) do { \
    float p0 = fexp2(sv[0]), p1 = fexp2(sv[1]); \
    float p2 = fexp2(sv[2]), p3 = fexp2(sv[3]); \
    l += (p0 + p1) + (p2 + p3); \
    union { float f; uint32_t u; } q0, q1, q2, q3; \
    q0.f = p0; q1.f = p1; q2.f = p2; q3.f = p3; \
    pp.u.x = pack_trunc(q0.u, q1.u); \
    pp.u.y = pack_trunc(q2.u, q3.u); \
} while (0)

// ---------------------------------------------------------------------------
// Kernel 2: flash attention, key-split, no-max softmax, 4 q-tiles per wave.
// Block = 256 threads (4 waves) covering 16 q-tiles; NQB=32 (tail guarded).
// One af ds_read + two h ds_read_b128 per key tile serve 4 independent
// QK->exp->PV chains (ILP hides LDS/MFMA/trans latency).
// Partial (l, O-bf16) per (b,qt,split); combine = plain sums.
// ---------------------------------------------------------------------------
template<int SPLITT>
__global__ __launch_bounds__(256, 4) void attn_kernel(
    const uint8_t* __restrict__ ws_in,
    uint8_t* __restrict__ ws_out)
{
    constexpr int TPS = NKT / SPLITT;
    constexpr int NST = TPS / STAGE_KT;
    __shared__ uint4 kvs4[STAGE_KT * 160];      // 12,800 B
    const uint2* kvs2 = (const uint2*)kvs4;

    const int tid = threadIdx.x;
    const int L = tid & 63, w = tid >> 6;
    const int lane16 = L & 15, g4 = L >> 4;

    const int bid = blockIdx.x;                 // NB*NQB*SPLITT blocks
    const int qblk = bid % NQB;
    const int bs = bid / NQB;
    const int b = bs / SPLITT, s = bs % SPLITT;
    const int qt0 = qblk * 16 + w * 4;          // wave owns qt0..qt0+3

    const uint4* kv4 = (const uint4*)ws_in;
    const uint2* gB  = (const uint2*)(ws_in + GB_OFF);
    float* part_l = (float*)(ws_out + PML_OFF);
    uint2* part_O = (uint2*)(ws_out + po_off(SPLITT));

    const bool vA = (qt0 + 0 < NKT), vB = (qt0 + 1 < NKT);
    const bool vC = (qt0 + 2 < NKT), vD = (qt0 + 3 < NKT);
    s16x4 bgA, bgB, bgC, bgD;
    { union { uint2 u; s16x4 v; } t; t.u = gB[(size_t)(b * NKT + (vA ? qt0 + 0 : 0)) * 64 + L]; bgA = t.v; }
    { union { uint2 u; s16x4 v; } t; t.u = gB[(size_t)(b * NKT + (vB ? qt0 + 1 : 0)) * 64 + L]; bgB = t.v; }
    { union { uint2 u; s16x4 v; } t; t.u = gB[(size_t)(b * NKT + (vC ? qt0 + 2 : 0)) * 64 + L]; bgC = t.v; }
    { union { uint2 u; s16x4 v; } t; t.u = gB[(size_t)(b * NKT + (vD ? qt0 + 3 : 0)) * 64 + L]; bgD = t.v; }

    float l_A = 0.f, l_B = 0.f, l_C = 0.f, l_D = 0.f;
    const f32x4 zz = {0, 0, 0, 0};
    f32x4 oA0 = {0,0,0,0}, oA1 = {0,0,0,0}, oA2 = {0,0,0,0}, oA3 = {0,0,0,0};
    f32x4 oB0 = {0,0,0,0}, oB1 = {0,0,0,0}, oB2 = {0,0,0,0}, oB3 = {0,0,0,0};
    f32x4 oC0 = {0,0,0,0}, oC1 = {0,0,0,0}, oC2 = {0,0,0,0}, oC3 = {0,0,0,0};
    f32x4 oD0 = {0,0,0,0}, oD1 = {0,0,0,0}, oD2 = {0,0,0,0}, oD3 = {0,0,0,0};

    const int kt0 = s * TPS;
    const uint4* stage_base = kv4 + (size_t)(b * NKT + kt0) * 160;

    for (int st = 0; st < NST; st++) {
        __syncthreads();                        // previous compute done with kvs
        {
            const uint4* src = stage_base + (size_t)st * (STAGE_KT * 160);
            uint4 tmp[3];
            #pragma unroll
            for (int i = 0; i < 3; i++) tmp[i] = src[tid + i * 256];
            uint4 tailv;
            if (tid < 32) tailv = src[768 + tid];
            #pragma unroll
            for (int i = 0; i < 3; i++) kvs4[tid + i * 256] = tmp[i];
            if (tid < 32) kvs4[768 + tid] = tailv;
        }
        __syncthreads();

        for (int ktl = 0; ktl < STAGE_KT; ktl++) {
            s16x4 af;
            { union { uint2 u; s16x4 v; } t; t.u = kvs2[ktl * 320 + L]; af = t.v; }

            f32x4 svA = __builtin_amdgcn_mfma_f32_16x16x16bf16_1k(af, bgA, zz, 0, 0, 0);
            f32x4 svB = __builtin_amdgcn_mfma_f32_16x16x16bf16_1k(af, bgB, zz, 0, 0, 0);
            f32x4 svC = __builtin_amdgcn_mfma_f32_16x16x16bf16_1k(af, bgC, zz, 0, 0, 0);
            f32x4 svD = __builtin_amdgcn_mfma_f32_16x16x16bf16_1k(af, bgD, zz, 0, 0, 0);

            union { uint2 u; s16x4 v; } ppA, ppB, ppC, ppD;
            SM_PACK(svA, l_A, ppA);
            SM_PACK(svB, l_B, ppB);
            SM_PACK(svC, l_C, ppC);
            SM_PACK(svD, l_D, ppD);

            // h fragments: 2x ds_read_b128, shared by all 4 q-tiles
            union { uint4 q; uint2 d[2]; } hu01, hu23;
            hu01.q = kvs4[ktl * 160 + 32 + L];
            hu23.q = kvs4[ktl * 160 + 96 + L];
            s16x4 h0, h1, h2, h3;
            { union { uint2 u; s16x4 v; } t; t.u = hu01.d[0]; h0 = t.v; }
            { union { uint2 u; s16x4 v; } t; t.u = hu01.d[1]; h1 = t.v; }
            { union { uint2 u; s16x4 v; } t; t.u = hu23.d[0]; h2 = t.v; }
            { union { uint2 u; s16x4 v; } t; t.u = hu23.d[1]; h3 = t.v; }

            oA0 = __builtin_amdgcn_mfma_f32_16x16x16bf16_1k(ppA.v, h0, oA0, 0, 0, 0);
            oA1 = __builtin_amdgcn_mfma_f32_16x16x16bf16_1k(ppA.v, h1, oA1, 0, 0, 0);
            oA2 = __builtin_amdgcn_mfma_f32_16x16x16bf16_1k(ppA.v, h2, oA2, 0, 0, 0);
            oA3 = __builtin_amdgcn_mfma_f32_16x16x16bf16_1k(ppA.v, h3, oA3, 0, 0, 0);
            oB0 = __builtin_amdgcn_mfma_f32_16x16x16bf16_1k(ppB.v, h0, oB0, 0, 0, 0);
            oB1 = __builtin_amdgcn_mfma_f32_16x16x16bf16_1k(ppB.v, h1, oB1, 0, 0, 0);
            oB2 = __builtin_amdgcn_mfma_f32_16x16x16bf16_1k(ppB.v, h2, oB2, 0, 0, 0);
            oB3 = __builtin_amdgcn_mfma_f32_16x16x16bf16_1k(ppB.v, h3, oB3, 0, 0, 0);
            oC0 = __builtin_amdgcn_mfma_f32_16x16x16bf16_1k(ppC.v, h0, oC0, 0, 0, 0);
            oC1 = __builtin_amdgcn_mfma_f32_16x16x16bf16_1k(ppC.v, h1, oC1, 0, 0, 0);
            oC2 = __builtin_amdgcn_mfma_f32_16x16x16bf16_1k(ppC.v, h2, oC2, 0, 0, 0);
            oC3 = __builtin_amdgcn_mfma_f32_16x16x16bf16_1k(ppC.v, h3, oC3, 0, 0, 0);
            oD0 = __builtin_amdgcn_mfma_f32_16x16x16bf16_1k(ppD.v, h0, oD0, 0, 0, 0);
            oD1 = __builtin_amdgcn_mfma_f32_16x16x16bf16_1k(ppD.v, h1, oD1, 0, 0, 0);
            oD2 = __builtin_amdgcn_mfma_f32_16x16x16bf16_1k(ppD.v, h2, oD2, 0, 0, 0);
            oD3 = __builtin_amdgcn_mfma_f32_16x16x16bf16_1k(ppD.v, h3, oD3, 0, 0, 0);
        }
    }

    // ---- epilogue: reduce l, store (l, O-bf16) partials per q-tile ----
#define STORE_QT(QTOFF, VALID, LV, O0, O1, O2, O3) do { \
    float ls = LV; \
    ls += __shfl_xor(ls, 16); \
    ls += __shfl_xor(ls, 32); \
    if (VALID) { \
        const size_t pslot = (size_t)(b * NKT + qt0 + (QTOFF)) * SPLITT + s; \
        if (g4 == 0) part_l[pslot * 16 + lane16] = ls; \
        uint2* obase = part_O + pslot * 256; \
        _Pragma("unroll") \
        for (int r = 0; r < 4; r++) { \
            const int row = g4 * 4 + r; \
            union { s16x4 v; uint2 u; } ou; \
            ou.v[0] = f2bf(O0[r]); ou.v[1] = f2bf(O1[r]); \
            ou.v[2] = f2bf(O2[r]); ou.v[3] = f2bf(O3[r]); \
            obase[row * 16 + lane16] = ou.u; \
        } \
    } \
} while (0)

    STORE_QT(0, vA, l_A, oA0, oA1, oA2, oA3);
    STORE_QT(1, vB, l_B, oB0, oB1, oB2, oB3);
    STORE_QT(2, vC, l_C, oC0, oC1, oC2, oC3);
    STORE_QT(3, vD, l_D, oD0, oD1, oD2, oD3);
#undef STORE_QT
}

// ---------------------------------------------------------------------------
// Kernel 3: combine splits (plain sums) + gamma/residual. Thread = (row, j);
// handles channels {j, j+16, j+32, j+48} packed in one uint2 per split.
// ---------------------------------------------------------------------------
template<int SPLITT>
__global__ __launch_bounds__(256) void combine_kernel(
    const float* __restrict__ x,
    const float* __restrict__ gammap,
    const uint8_t* __restrict__ ws,
    float* __restrict__ out)
{
    const int idx = blockIdx.x * 256 + threadIdx.x;   // 0 .. 255,999
    const int j = idx & 15;
    const int row_g = idx >> 4;                        // 0..15999
    const int b = row_g / NN;
    const int row = row_g - b * NN;
    const int qt = row >> 4, q = row & 15;

    const float* part_l = (const float*)(ws + PML_OFF);
    const uint2* part_O = (const uint2*)(ws + po_off(SPLITT));
    const size_t pbase = (size_t)(b * NKT + qt) * SPLITT;

    float Lsum = 0.f, O0 = 0.f, O1 = 0.f, O2 = 0.f, O3 = 0.f;
    #pragma unroll
    for (int s = 0; s < SPLITT; s++) {
        Lsum += part_l[(pbase + s) * 16 + q];
        uint2 u = part_O[(pbase + s) * 256 + q * 16 + j];
        O0 += __uint_as_float(u.x << 16);
        O1 += __uint_as_float(u.x & 0xffff0000u);
        O2 += __uint_as_float(u.y << 16);
        O3 += __uint_as_float(u.y & 0xffff0000u);
    }
    const float inv = gammap[0] / Lsum;
    const size_t base = (size_t)row_g * 64 + j;
    out[base +  0] = O0 * inv + x[base +  0];
    out[base + 16] = O1 * inv + x[base + 16];
    out[base + 32] = O2 * inv + x[base + 32];
    out[base + 48] = O3 * inv + x[base + 48];
}

extern "C" void kernel_launch(void* const* d_in, const int* in_sizes, int n_in,
                              void* d_out, int out_size, void* d_ws, size_t ws_size,
                              hipStream_t stream) {
    const float* x     = (const float*)d_in[0];
    const float* Wf    = (const float*)d_in[1];
    const float* Wg    = (const float*)d_in[2];
    const float* Wh    = (const float*)d_in[3];
    const float* gamma = (const float*)d_in[4];
    float* out = (float*)d_out;
    uint8_t* ws = (uint8_t*)d_ws;

    proj_kernel<<<250, 256, 0, stream>>>(x, Wf, Wg, Wh, ws);

    const size_t need20 = po_off(20) + po_bytes(20);   // ~46.6 MB (known to fit)
    const size_t need10 = po_off(10) + po_bytes(10);   // ~24.2 MB (known safe)
    if (ws_size >= need20) {
        attn_kernel<20><<<NB * NQB * 20, 256, 0, stream>>>(ws, ws);
        combine_kernel<20><<<(NB * NN * 16) / 256, 256, 0, stream>>>(x, gamma, ws, out);
    } else if (ws_size >= need10) {
        attn_kernel<10><<<NB * NQB * 10, 256, 0, stream>>>(ws, ws);
        combine_kernel<10><<<(NB * NN * 16) / 256, 256, 0, stream>>>(x, gamma, ws, out);
    } else {
        attn_kernel<5><<<NB * NQB * 5, 256, 0, stream>>>(ws, ws);
        combine_kernel<5><<<(NB * NN * 16) / 256, 256, 0, stream>>>(x, gamma, ws, out);
    }
}

// Round 11
// 60.539 us; speedup vs baseline: 3.0363x; 3.0363x over previous
//
#include <hip/hip_runtime.h>
#include <stdint.h>
#include <stddef.h>

#define NB 2
#define NN 8000
#define NC 64
#define NKT 500          // N/16 key tiles
#define STAGE_KT 5       // key tiles per LDS stage buffer (12.8 KB)
#define LOG2E 1.44269504f
#define NQB 42           // ceil(500 qtiles / 12 per block)

// ---- workspace layout (bytes) ----
// kv per tile (2560 B): f frag (512 B) + h01 interleaved (1024 B) + h23 (1024 B)
#define KV_BYTES  ((size_t)NB * NKT * 2560)         // 2,560,000
#define GB_OFF    KV_BYTES                          // g frags
#define GB_BYTES  ((size_t)NB * NKT * 64 * 8)       // 512,000
#define PML_OFF   (GB_OFF + GB_BYTES)               // l[16] per (b,qt,split)

__host__ __device__ constexpr size_t pml_bytes(int s) { return (size_t)NB * NKT * s * 16 * 4; }
__host__ __device__ constexpr size_t po_off(int s)    { return PML_OFF + pml_bytes(s); }
// partial O: per (b,qt,split) 16 rows x 16 j x uint2 (4 bf16) = 2048 B
__host__ __device__ constexpr size_t po_bytes(int s)  { return (size_t)NB * NKT * s * 2048; }

typedef float f32x4 __attribute__((ext_vector_type(4)));
typedef short s16x4 __attribute__((ext_vector_type(4)));

__device__ inline short f2bf(float f) {                // RNE to bf16 (bitwise, proven)
    union { float f; uint32_t u; } v; v.f = f;
    uint32_t u = v.u + 0x7FFFu + ((v.u >> 16) & 1u);
    return (short)(u >> 16);
}
// raw v_exp_f32: 2^x in ONE instruction (libm wrapper is ~10 VALU ops).
__device__ inline float fexp2(float x) { return __builtin_amdgcn_exp2f(x); }
// pack {hi16(a), hi16(b)} -> one word in ONE v_perm_b32 (truncation to bf16)
__device__ inline uint32_t pack_trunc(uint32_t a_lo, uint32_t b_hi) {
    return __builtin_amdgcn_perm(b_hi, a_lo, 0x07060302u);
}

// ---------------------------------------------------------------------------
// Kernel 1: projections (R8-exact). Grid 250 x 256; per block 4 key tiles,
// one wave each: f = x(Wf*log2e), g = xWg, h = xWh, stored in MFMA fragment
// order (bf16). kv per tile: f A-frag (64 uint2) | h01 (64 uint4) | h23;
// gB[b][qt][lane] = g B-frag. mfma_f32_16x16x16_bf16 maps: A row=lane&15,
// k=(lane>>4)*4+e ; B col=lane&15,k=(lane>>4)*4+e ; C/D col=lane&15,
// row=(lane>>4)*4+reg.
// ---------------------------------------------------------------------------
__global__ __launch_bounds__(256) void proj_kernel(
    const float* __restrict__ x,
    const float* __restrict__ Wf,
    const float* __restrict__ Wg,
    const float* __restrict__ Wh,
    uint8_t* __restrict__ ws)
{
    __shared__ float Wh_s[64][68];
    __shared__ float Wf_s[64][8];
    __shared__ float Wg_s[64][8];
    __shared__ float x_s[4][16][68];
    __shared__ float h_s[4][16][68];

    const int tid = threadIdx.x;
    const int L = tid & 63, w = tid >> 6;
    const int lane16 = L & 15, g4 = L >> 4;

    for (int i = tid; i < 64 * 64; i += 256) Wh_s[i >> 6][i & 63] = Wh[i];
    for (int i = tid; i < 64 * 8; i += 256) {
        Wf_s[i >> 3][i & 7] = Wf[i] * LOG2E;   // scores in log2 domain
        Wg_s[i >> 3][i & 7] = Wg[i];
    }

    const int ktg = blockIdx.x * 4 + w;      // 0..999
    const int b = ktg / NKT, ktb = ktg % NKT;
    const float* xsrc = x + ((size_t)b * NN + (size_t)ktb * 16) * NC;

    #pragma unroll
    for (int i = 0; i < 4; i++) {
        int F = i * 256 + L * 4;
        f32x4 v = *(const f32x4*)(xsrc + F);
        *(f32x4*)&x_s[w][F >> 6][F & 63] = v;
    }
    __syncthreads();

    uint2* kv2 = (uint2*)ws;
    uint4* kv4 = (uint4*)ws;
    uint2* gB  = (uint2*)(ws + GB_OFF);
    const size_t kt = (size_t)(b * NKT + ktb);

    {
        float fa0 = 0, fa1 = 0, fa2 = 0, fa3 = 0;
        float ga0 = 0, ga1 = 0, ga2 = 0, ga3 = 0;
        const int d0 = (g4 & 1) * 4;
        #pragma unroll 4
        for (int k = 0; k < 64; k++) {
            float xv = x_s[w][lane16][k];
            fa0 += xv * Wf_s[k][d0 + 0]; fa1 += xv * Wf_s[k][d0 + 1];
            fa2 += xv * Wf_s[k][d0 + 2]; fa3 += xv * Wf_s[k][d0 + 3];
            ga0 += xv * Wg_s[k][d0 + 0]; ga1 += xv * Wg_s[k][d0 + 1];
            ga2 += xv * Wg_s[k][d0 + 2]; ga3 += xv * Wg_s[k][d0 + 3];
        }
        const bool valid = (g4 < 2);
        union { s16x4 v; uint2 u; } fp, gp;
        fp.v[0] = valid ? f2bf(fa0) : (short)0;
        fp.v[1] = valid ? f2bf(fa1) : (short)0;
        fp.v[2] = valid ? f2bf(fa2) : (short)0;
        fp.v[3] = valid ? f2bf(fa3) : (short)0;
        gp.v[0] = valid ? f2bf(ga0) : (short)0;
        gp.v[1] = valid ? f2bf(ga1) : (short)0;
        gp.v[2] = valid ? f2bf(ga2) : (short)0;
        gp.v[3] = valid ? f2bf(ga3) : (short)0;
        kv2[kt * 320 + L] = fp.u;              // f: first 64 uint2 of the tile
        gB[kt * 64 + L] = gp.u;
    }

    {
        float ha[16];
        #pragma unroll
        for (int i = 0; i < 16; i++) ha[i] = 0.f;
        const int c0 = g4 * 16;
        for (int k = 0; k < 64; k++) {
            float xv = x_s[w][lane16][k];
            const f32x4 w0 = *(const f32x4*)&Wh_s[k][c0 + 0];
            const f32x4 w1 = *(const f32x4*)&Wh_s[k][c0 + 4];
            const f32x4 w2 = *(const f32x4*)&Wh_s[k][c0 + 8];
            const f32x4 w3 = *(const f32x4*)&Wh_s[k][c0 + 12];
            #pragma unroll
            for (int e = 0; e < 4; e++) {
                ha[e]      += xv * w0[e];
                ha[4 + e]  += xv * w1[e];
                ha[8 + e]  += xv * w2[e];
                ha[12 + e] += xv * w3[e];
            }
        }
        #pragma unroll
        for (int i = 0; i < 4; i++) {
            f32x4 t; t[0] = ha[4*i]; t[1] = ha[4*i+1]; t[2] = ha[4*i+2]; t[3] = ha[4*i+3];
            *(f32x4*)&h_s[w][lane16][c0 + 4 * i] = t;
        }
    }
    __syncthreads();

    {
        union { s16x4 v; uint2 u; } hp[4];
        #pragma unroll
        for (int cb = 0; cb < 4; cb++)
            #pragma unroll
            for (int e = 0; e < 4; e++)
                hp[cb].v[e] = f2bf(h_s[w][g4 * 4 + e][cb * 16 + lane16]);
        uint4 h01, h23;
        h01.x = hp[0].u.x; h01.y = hp[0].u.y; h01.z = hp[1].u.x; h01.w = hp[1].u.y;
        h23.x = hp[2].u.x; h23.y = hp[2].u.y; h23.z = hp[3].u.x; h23.w = hp[3].u.y;
        kv4[kt * 160 + 32 + L] = h01;
        kv4[kt * 160 + 96 + L] = h23;
    }
}

// softmax + pack for one q-tile's 4 scores
#define SM_PACK(sv, l, pp) do { \
    float p0 = fexp2(sv[0]), p1 = fexp2(sv[1]); \
    float p2 = fexp2(sv[2]), p3 = fexp2(sv[3]); \
    l += (p0 + p1) + (p2 + p3); \
    union { float f; uint32_t u; } q0, q1, q2, q3; \
    q0.f = p0; q1.f = p1; q2.f = p2; q3.f = p3; \
    pp.u.x = pack_trunc(q0.u, q1.u); \
    pp.u.y = pack_trunc(q2.u, q3.u); \
} while (0)

// ---------------------------------------------------------------------------
// Kernel 2: flash attention, key-split, no-max softmax, 3 q-tiles per wave.
// Block = 256 threads (4 waves) covering 12 q-tiles; NQB=42 (tail guarded).
// One af ds_read + two h ds_read_b128 per key tile serve 3 independent
// QK->exp->PV chains. __launch_bounds__(256,3) leaves ~170 VGPR so the
// 12 f32x4 accumulators stay in registers (R10's (256,4) cap caused scratch
// spill: FETCH 232 MB. Tripwire: attn FETCH>30MB => spilled again).
// ---------------------------------------------------------------------------
template<int SPLITT>
__global__ __launch_bounds__(256, 3) void attn_kernel(
    const uint8_t* __restrict__ ws_in,
    uint8_t* __restrict__ ws_out)
{
    constexpr int TPS = NKT / SPLITT;
    constexpr int NST = TPS / STAGE_KT;
    __shared__ uint4 kvs4[STAGE_KT * 160];      // 12,800 B
    const uint2* kvs2 = (const uint2*)kvs4;

    const int tid = threadIdx.x;
    const int L = tid & 63, w = tid >> 6;
    const int lane16 = L & 15, g4 = L >> 4;

    const int bid = blockIdx.x;                 // NB*NQB*SPLITT blocks
    const int qblk = bid % NQB;
    const int bs = bid / NQB;
    const int b = bs / SPLITT, s = bs % SPLITT;
    const int qt0 = qblk * 12 + w * 3;          // wave owns qt0..qt0+2

    const uint4* kv4 = (const uint4*)ws_in;
    const uint2* gB  = (const uint2*)(ws_in + GB_OFF);
    float* part_l = (float*)(ws_out + PML_OFF);
    uint2* part_O = (uint2*)(ws_out + po_off(SPLITT));

    const bool vA = (qt0 + 0 < NKT), vB = (qt0 + 1 < NKT), vC = (qt0 + 2 < NKT);
    s16x4 bgA, bgB, bgC;
    { union { uint2 u; s16x4 v; } t; t.u = gB[(size_t)(b * NKT + (vA ? qt0 + 0 : 0)) * 64 + L]; bgA = t.v; }
    { union { uint2 u; s16x4 v; } t; t.u = gB[(size_t)(b * NKT + (vB ? qt0 + 1 : 0)) * 64 + L]; bgB = t.v; }
    { union { uint2 u; s16x4 v; } t; t.u = gB[(size_t)(b * NKT + (vC ? qt0 + 2 : 0)) * 64 + L]; bgC = t.v; }

    float l_A = 0.f, l_B = 0.f, l_C = 0.f;
    const f32x4 zz = {0, 0, 0, 0};
    f32x4 oA0 = {0,0,0,0}, oA1 = {0,0,0,0}, oA2 = {0,0,0,0}, oA3 = {0,0,0,0};
    f32x4 oB0 = {0,0,0,0}, oB1 = {0,0,0,0}, oB2 = {0,0,0,0}, oB3 = {0,0,0,0};
    f32x4 oC0 = {0,0,0,0}, oC1 = {0,0,0,0}, oC2 = {0,0,0,0}, oC3 = {0,0,0,0};

    const int kt0 = s * TPS;
    const uint4* stage_base = kv4 + (size_t)(b * NKT + kt0) * 160;

    for (int st = 0; st < NST; st++) {
        __syncthreads();                        // previous compute done with kvs
        {
            const uint4* src = stage_base + (size_t)st * (STAGE_KT * 160);
            uint4 tmp[3];
            #pragma unroll
            for (int i = 0; i < 3; i++) tmp[i] = src[tid + i * 256];
            uint4 tailv;
            if (tid < 32) tailv = src[768 + tid];
            #pragma unroll
            for (int i = 0; i < 3; i++) kvs4[tid + i * 256] = tmp[i];
            if (tid < 32) kvs4[768 + tid] = tailv;
        }
        __syncthreads();

        #pragma unroll
        for (int ktl = 0; ktl < STAGE_KT; ktl++) {
            s16x4 af;
            { union { uint2 u; s16x4 v; } t; t.u = kvs2[ktl * 320 + L]; af = t.v; }

            f32x4 svA = __builtin_amdgcn_mfma_f32_16x16x16bf16_1k(af, bgA, zz, 0, 0, 0);
            f32x4 svB = __builtin_amdgcn_mfma_f32_16x16x16bf16_1k(af, bgB, zz, 0, 0, 0);
            f32x4 svC = __builtin_amdgcn_mfma_f32_16x16x16bf16_1k(af, bgC, zz, 0, 0, 0);

            union { uint2 u; s16x4 v; } ppA, ppB, ppC;
            SM_PACK(svA, l_A, ppA);
            SM_PACK(svB, l_B, ppB);
            SM_PACK(svC, l_C, ppC);

            // h fragments: 2x ds_read_b128, shared by all 3 q-tiles
            union { uint4 q; uint2 d[2]; } hu01, hu23;
            hu01.q = kvs4[ktl * 160 + 32 + L];
            hu23.q = kvs4[ktl * 160 + 96 + L];
            s16x4 h0, h1, h2, h3;
            { union { uint2 u; s16x4 v; } t; t.u = hu01.d[0]; h0 = t.v; }
            { union { uint2 u; s16x4 v; } t; t.u = hu01.d[1]; h1 = t.v; }
            { union { uint2 u; s16x4 v; } t; t.u = hu23.d[0]; h2 = t.v; }
            { union { uint2 u; s16x4 v; } t; t.u = hu23.d[1]; h3 = t.v; }

            oA0 = __builtin_amdgcn_mfma_f32_16x16x16bf16_1k(ppA.v, h0, oA0, 0, 0, 0);
            oA1 = __builtin_amdgcn_mfma_f32_16x16x16bf16_1k(ppA.v, h1, oA1, 0, 0, 0);
            oA2 = __builtin_amdgcn_mfma_f32_16x16x16bf16_1k(ppA.v, h2, oA2, 0, 0, 0);
            oA3 = __builtin_amdgcn_mfma_f32_16x16x16bf16_1k(ppA.v, h3, oA3, 0, 0, 0);
            oB0 = __builtin_amdgcn_mfma_f32_16x16x16bf16_1k(ppB.v, h0, oB0, 0, 0, 0);
            oB1 = __builtin_amdgcn_mfma_f32_16x16x16bf16_1k(ppB.v, h1, oB1, 0, 0, 0);
            oB2 = __builtin_amdgcn_mfma_f32_16x16x16bf16_1k(ppB.v, h2, oB2, 0, 0, 0);
            oB3 = __builtin_amdgcn_mfma_f32_16x16x16bf16_1k(ppB.v, h3, oB3, 0, 0, 0);
            oC0 = __builtin_amdgcn_mfma_f32_16x16x16bf16_1k(ppC.v, h0, oC0, 0, 0, 0);
            oC1 = __builtin_amdgcn_mfma_f32_16x16x16bf16_1k(ppC.v, h1, oC1, 0, 0, 0);
            oC2 = __builtin_amdgcn_mfma_f32_16x16x16bf16_1k(ppC.v, h2, oC2, 0, 0, 0);
            oC3 = __builtin_amdgcn_mfma_f32_16x16x16bf16_1k(ppC.v, h3, oC3, 0, 0, 0);
        }
    }

    // ---- epilogue: reduce l, store (l, O-bf16) partials per q-tile ----
#define STORE_QT(QTOFF, VALID, LV, O0, O1, O2, O3) do { \
    float ls = LV; \
    ls += __shfl_xor(ls, 16); \
    ls += __shfl_xor(ls, 32); \
    if (VALID) { \
        const size_t pslot = (size_t)(b * NKT + qt0 + (QTOFF)) * SPLITT + s; \
        if (g4 == 0) part_l[pslot * 16 + lane16] = ls; \
        uint2* obase = part_O + pslot * 256; \
        _Pragma("unroll") \
        for (int r = 0; r < 4; r++) { \
            const int row = g4 * 4 + r; \
            union { s16x4 v; uint2 u; } ou; \
            ou.v[0] = f2bf(O0[r]); ou.v[1] = f2bf(O1[r]); \
            ou.v[2] = f2bf(O2[r]); ou.v[3] = f2bf(O3[r]); \
            obase[row * 16 + lane16] = ou.u; \
        } \
    } \
} while (0)

    STORE_QT(0, vA, l_A, oA0, oA1, oA2, oA3);
    STORE_QT(1, vB, l_B, oB0, oB1, oB2, oB3);
    STORE_QT(2, vC, l_C, oC0, oC1, oC2, oC3);
#undef STORE_QT
}

// ---------------------------------------------------------------------------
// Kernel 3: combine splits (plain sums) + gamma/residual. Thread = (row, j);
// handles channels {j, j+16, j+32, j+48} packed in one uint2 per split.
// ---------------------------------------------------------------------------
template<int SPLITT>
__global__ __launch_bounds__(256) void combine_kernel(
    const float* __restrict__ x,
    const float* __restrict__ gammap,
    const uint8_t* __restrict__ ws,
    float* __restrict__ out)
{
    const int idx = blockIdx.x * 256 + threadIdx.x;   // 0 .. 255,999
    const int j = idx & 15;
    const int row_g = idx >> 4;                        // 0..15999
    const int b = row_g / NN;
    const int row = row_g - b * NN;
    const int qt = row >> 4, q = row & 15;

    const float* part_l = (const float*)(ws + PML_OFF);
    const uint2* part_O = (const uint2*)(ws + po_off(SPLITT));
    const size_t pbase = (size_t)(b * NKT + qt) * SPLITT;

    float Lsum = 0.f, O0 = 0.f, O1 = 0.f, O2 = 0.f, O3 = 0.f;
    #pragma unroll
    for (int s = 0; s < SPLITT; s++) {
        Lsum += part_l[(pbase + s) * 16 + q];
        uint2 u = part_O[(pbase + s) * 256 + q * 16 + j];
        O0 += __uint_as_float(u.x << 16);
        O1 += __uint_as_float(u.x & 0xffff0000u);
        O2 += __uint_as_float(u.y << 16);
        O3 += __uint_as_float(u.y & 0xffff0000u);
    }
    const float inv = gammap[0] / Lsum;
    const size_t base = (size_t)row_g * 64 + j;
    out[base +  0] = O0 * inv + x[base +  0];
    out[base + 16] = O1 * inv + x[base + 16];
    out[base + 32] = O2 * inv + x[base + 32];
    out[base + 48] = O3 * inv + x[base + 48];
}

extern "C" void kernel_launch(void* const* d_in, const int* in_sizes, int n_in,
                              void* d_out, int out_size, void* d_ws, size_t ws_size,
                              hipStream_t stream) {
    const float* x     = (const float*)d_in[0];
    const float* Wf    = (const float*)d_in[1];
    const float* Wg    = (const float*)d_in[2];
    const float* Wh    = (const float*)d_in[3];
    const float* gamma = (const float*)d_in[4];
    float* out = (float*)d_out;
    uint8_t* ws = (uint8_t*)d_ws;

    proj_kernel<<<250, 256, 0, stream>>>(x, Wf, Wg, Wh, ws);

    const size_t need20 = po_off(20) + po_bytes(20);   // ~46.6 MB (known to fit)
    const size_t need10 = po_off(10) + po_bytes(10);   // ~24.2 MB (known safe)
    if (ws_size >= need20) {
        attn_kernel<20><<<NB * NQB * 20, 256, 0, stream>>>(ws, ws);
        combine_kernel<20><<<(NB * NN * 16) / 256, 256, 0, stream>>>(x, gamma, ws, out);
    } else if (ws_size >= need10) {
        attn_kernel<10><<<NB * NQB * 10, 256, 0, stream>>>(ws, ws);
        combine_kernel<10><<<(NB * NN * 16) / 256, 256, 0, stream>>>(x, gamma, ws, out);
    } else {
        attn_kernel<5><<<NB * NQB * 5, 256, 0, stream>>>(ws, ws);
        combine_kernel<5><<<(NB * NN * 16) / 256, 256, 0, stream>>>(x, gamma, ws, out);
    }
}